// Round 1
// baseline (260.393 us; speedup 1.0000x reference)
//
#include <hip/hip_runtime.h>
#include <stdint.h>

#define B_ 8
#define H_ 128
#define W_ 128
#define D_ 128
#define N_ (H_*W_)
#define M_ (B_*N_)   // 131072 rows total

typedef __attribute__((ext_vector_type(8))) short short8;
typedef __attribute__((ext_vector_type(4))) float floatx4;

typedef const __attribute__((address_space(1))) void* gas_t;
typedef __attribute__((address_space(3))) void* las_t;

__device__ inline unsigned short f2bf(float f){
  union { float f; unsigned int i; } c; c.f = f;
  unsigned int x = c.i;
  x += 0x7FFF + ((x >> 16) & 1);   // RNE
  return (unsigned short)(x >> 16);
}
__device__ inline float bflo(unsigned int u){
  union { unsigned int i; float f; } c; c.i = u << 16; return c.f;
}
__device__ inline float bfhi(unsigned int u){
  union { unsigned int i; float f; } c; c.i = u & 0xFFFF0000u; return c.f;
}

// ---------------- kernel 0: W -> W^T bf16 ----------------
__global__ void wtrans_kernel(const float* __restrict__ Wq, const float* __restrict__ Wk,
                              const float* __restrict__ Wv, unsigned short* __restrict__ Wt){
  const float* src = blockIdx.x == 0 ? Wq : (blockIdx.x == 1 ? Wk : Wv);
  unsigned short* dst = Wt + blockIdx.x * (D_*D_);
  const int i = blockIdx.y * 256 + threadIdx.x;
  const int k = i >> 7, n = i & 127;
  dst[n*D_ + k] = f2bf(src[i]);
}

// ---------------- kernel 1: FUSED QKV projection ----------------
// One block = 128-row tile, computes Q, K, AND V for it -> x read ONCE (was 3x).
// LDS: A [0,16384) ushorts (persists), B [16384,32768) restaged per `which`,
// then reused as epilogue buffer in two 64-row halves.
__global__ __launch_bounds__(256, 2) void qkv_gemm_kernel(
    const float* __restrict__ x, const unsigned short* __restrict__ Wt,
    const float* __restrict__ bq, const float* __restrict__ bk, const float* __restrict__ bv,
    unsigned short* __restrict__ Q, unsigned short* __restrict__ K, unsigned short* __restrict__ V)
{
  const int rowTile = blockIdx.x;

  __shared__ unsigned short lds[32768];  // 64 KB -> 2 blocks/CU

  const int t = threadIdx.x;
  const int wave = t >> 6, lane = t & 63;

  // ---- A stage (once): fp32 x -> bf16, swizzled ds_write_b128
  {
    const float* xrow = x + (size_t)rowTile * 128 * D_;
    #pragma unroll
    for (int p = 0; p < 8; ++p){
      int s = p*256 + t;
      int r = s >> 4, cp = s & 15, c = cp ^ (r & 7);
      const float* gp = xrow + r*D_ + c*8;
      float4 f0 = *(const float4*)gp;
      float4 f1 = *(const float4*)(gp + 4);
      uint4 pk;
      pk.x = (unsigned)f2bf(f0.x) | ((unsigned)f2bf(f0.y) << 16);
      pk.y = (unsigned)f2bf(f0.z) | ((unsigned)f2bf(f0.w) << 16);
      pk.z = (unsigned)f2bf(f1.x) | ((unsigned)f2bf(f1.y) << 16);
      pk.w = (unsigned)f2bf(f1.z) | ((unsigned)f2bf(f1.w) << 16);
      *(uint4*)&lds[s*8] = pk;
    }
  }

  const int wm = (wave >> 1) * 64, wn = (wave & 1) * 64;
  const int m0 = lane & 15, quad = lane >> 4;

  #pragma unroll
  for (int which = 0; which < 3; ++which){
    const float* bias = which == 0 ? bq : (which == 1 ? bk : bv);
    unsigned short* Out = which == 0 ? Q : (which == 1 ? K : V);
    const unsigned short* Wsel = Wt + which * (D_*D_);

    // ---- B stage: async global->LDS, 16B/lane
    #pragma unroll
    for (int p = 0; p < 8; ++p){
      int s = p*256 + t;                 // 16B chunk id
      int n = s >> 4, cp = s & 15, c = cp ^ (n & 7);
      const unsigned short* gp = Wsel + n*128 + c*8;
      unsigned short* lp = (unsigned short*)lds + 16384 + p*2048 + wave*512;
      __builtin_amdgcn_global_load_lds((gas_t)(const void*)gp, (las_t)(void*)lp, 16, 0, 0);
    }
    __syncthreads();

    floatx4 acc[4][4] = {};
    #pragma unroll
    for (int kk = 0; kk < 4; ++kk){
      short8 a[4], b[4];
      #pragma unroll
      for (int i = 0; i < 4; ++i){
        int row = wm + i*16 + m0;
        int c = (kk*4 + quad) ^ (row & 7);
        a[i] = *(const short8*)&lds[row*128 + c*8];
      }
      #pragma unroll
      for (int j = 0; j < 4; ++j){
        int n = wn + j*16 + m0;
        int c = (kk*4 + quad) ^ (n & 7);
        b[j] = *(const short8*)&lds[16384 + n*128 + c*8];
      }
      #pragma unroll
      for (int i = 0; i < 4; ++i)
        #pragma unroll
        for (int j = 0; j < 4; ++j)
          acc[i][j] = __builtin_amdgcn_mfma_f32_16x16x32_bf16(a[i], b[j], acc[i][j], 0, 0, 0);
    }

    // ---- epilogue: reuse B region (16384 ushorts) in two 64-row halves
    __syncthreads();   // everyone done reading B
    unsigned short* Outp = Out + (size_t)rowTile * 128 * D_;
    #pragma unroll
    for (int half = 0; half < 2; ++half){
      if ((wave >> 1) == half){          // waves owning rows half*64 .. half*64+63
        #pragma unroll
        for (int j = 0; j < 4; ++j){
          const int col = wn + j*16 + m0;
          const float bb = bias[col];
          #pragma unroll
          for (int i = 0; i < 4; ++i){
            #pragma unroll
            for (int r = 0; r < 4; ++r){
              int lrow = i*16 + quad*4 + r;   // local row within half
              lds[16384 + lrow*136 + col] = f2bf(acc[i][j][r] + bb);
            }
          }
        }
      }
      __syncthreads();
      #pragma unroll
      for (int p = 0; p < 4; ++p){
        int rr = p*16 + (t >> 4), cc = t & 15;
        uint4 vv = *(const uint4*)&lds[16384 + rr*136 + cc*8];
        *(uint4*)(Outp + half*8192 + p*2048 + t*8) = vv;
      }
      __syncthreads();
    }
  }
}

// ---------------- kernel 2: 3x3 window attention ----------------
// 8 threads/pixel, 16 dims each. All 9 K loads batch-issued (18 uint4 = 72 VGPR),
// then all 9 V loads batch-issued BEFORE softmax (addresses independent of scores).
// Previous version: VGPR=44 -> compiler serialized loads (~2 in flight) -> 36% BW.
// This version: ~18 outstanding 16B loads/thread, cap 128 VGPR via launch_bounds.
__global__ __launch_bounds__(256, 4) void attn_kernel(
    const unsigned short* __restrict__ Q, const unsigned short* __restrict__ K,
    const unsigned short* __restrict__ V, float* __restrict__ out)
{
  const int t = threadIdx.x;
  const int e8 = t & 7;                      // which 16-dim chunk
  const int pix = blockIdx.x * 32 + (t >> 3);
  const int w = pix & 127;
  const int h = (pix >> 7) & 127;
  const float scale = 0.08838834764831845f;  // 1/sqrt(128)

  const size_t off = (size_t)pix * D_ + e8 * 16;

  // ---- q: 2x16B, scaled
  float q[16];
  {
    const unsigned short* qp = Q + off;
    uint4 u0 = *(const uint4*)qp;
    uint4 u1 = *(const uint4*)(qp + 8);
    unsigned uu[8] = {u0.x, u0.y, u0.z, u0.w, u1.x, u1.y, u1.z, u1.w};
    #pragma unroll
    for (int e = 0; e < 8; ++e){
      q[e*2]     = bflo(uu[e]) * scale;
      q[e*2 + 1] = bfhi(uu[e]) * scale;
    }
  }

  // ---- batch-issue ALL 9 K loads (OOB -> zero, matches zero-padded reference)
  uint4 ku[9][2];
  #pragma unroll
  for (int i = 0; i < 9; ++i){
    const int dy = i/3 - 1, dx = i%3 - 1;
    const bool ok = ((unsigned)(h + dy) < 128u) && ((unsigned)(w + dx) < 128u);
    if (ok){
      const unsigned short* kp = K + off + (dy*W_ + dx) * D_;
      ku[i][0] = *(const uint4*)kp;
      ku[i][1] = *(const uint4*)(kp + 8);
    } else {
      ku[i][0] = make_uint4(0u,0u,0u,0u);
      ku[i][1] = make_uint4(0u,0u,0u,0u);
    }
  }

  // ---- partial dot products (16 dims), then 8-lane reduce
  float s[9];
  #pragma unroll
  for (int i = 0; i < 9; ++i){
    unsigned uu[8] = {ku[i][0].x, ku[i][0].y, ku[i][0].z, ku[i][0].w,
                      ku[i][1].x, ku[i][1].y, ku[i][1].z, ku[i][1].w};
    float acc = 0.f;
    #pragma unroll
    for (int e = 0; e < 8; ++e){
      acc += q[e*2]     * bflo(uu[e]);
      acc += q[e*2 + 1] * bfhi(uu[e]);
    }
    s[i] = acc;
  }
  #pragma unroll
  for (int i = 0; i < 9; ++i){
    s[i] += __shfl_xor(s[i], 1, 64);
    s[i] += __shfl_xor(s[i], 2, 64);
    s[i] += __shfl_xor(s[i], 4, 64);
  }

  // ---- batch-issue ALL 9 V loads now; they fly while softmax computes
  uint4 vu[9][2];
  #pragma unroll
  for (int i = 0; i < 9; ++i){
    const int dy = i/3 - 1, dx = i%3 - 1;
    const bool ok = ((unsigned)(h + dy) < 128u) && ((unsigned)(w + dx) < 128u);
    if (ok){
      const unsigned short* vp = V + off + (dy*W_ + dx) * D_;
      vu[i][0] = *(const uint4*)vp;
      vu[i][1] = *(const uint4*)(vp + 8);
    } else {
      vu[i][0] = make_uint4(0u,0u,0u,0u);
      vu[i][1] = make_uint4(0u,0u,0u,0u);
    }
  }

  // ---- softmax (OOB score is exactly 0, participates with v=0 — ref semantics)
  float m = s[0];
  #pragma unroll
  for (int i = 1; i < 9; ++i) m = fmaxf(m, s[i]);
  float p[9]; float l = 0.f;
  #pragma unroll
  for (int i = 0; i < 9; ++i){ p[i] = __expf(s[i] - m); l += p[i]; }
  const float inv = 1.f / l;

  // ---- PV accumulate (zeroed OOB V contributes 0)
  float o[16];
  #pragma unroll
  for (int d = 0; d < 16; ++d) o[d] = 0.f;
  #pragma unroll
  for (int i = 0; i < 9; ++i){
    const float pi = p[i];
    unsigned uu[8] = {vu[i][0].x, vu[i][0].y, vu[i][0].z, vu[i][0].w,
                      vu[i][1].x, vu[i][1].y, vu[i][1].z, vu[i][1].w};
    #pragma unroll
    for (int e = 0; e < 8; ++e){
      o[e*2]     += pi * bflo(uu[e]);
      o[e*2 + 1] += pi * bfhi(uu[e]);
    }
  }

  float* op = out + off;
  #pragma unroll
  for (int c = 0; c < 4; ++c){
    float4 v4 = make_float4(o[c*4]*inv, o[c*4+1]*inv, o[c*4+2]*inv, o[c*4+3]*inv);
    *(float4*)(op + c*4) = v4;
  }
}

extern "C" void kernel_launch(void* const* d_in, const int* in_sizes, int n_in,
                              void* d_out, int out_size, void* d_ws, size_t ws_size,
                              hipStream_t stream)
{
  const float* x  = (const float*)d_in[0];
  const float* Wq = (const float*)d_in[1];
  const float* bq = (const float*)d_in[2];
  const float* Wk = (const float*)d_in[3];
  const float* bk = (const float*)d_in[4];
  const float* Wv = (const float*)d_in[5];
  const float* bv = (const float*)d_in[6];
  float* out = (float*)d_out;

  char* ws = (char*)d_ws;
  unsigned short* Wt = (unsigned short*)ws;                                   // 96 KB
  unsigned short* Q  = (unsigned short*)(ws + (1<<17));
  unsigned short* K  = (unsigned short*)(ws + (1<<17) + (size_t)M_*D_*2);
  unsigned short* V  = (unsigned short*)(ws + (1<<17) + (size_t)2*M_*D_*2);   // ~96.1 MB

  hipLaunchKernelGGL(wtrans_kernel, dim3(3, 64), dim3(256), 0, stream, Wq, Wk, Wv, Wt);
  hipLaunchKernelGGL(qkv_gemm_kernel, dim3(M_/128), dim3(256), 0, stream,
                     x, Wt, bq, bk, bv, Q, K, V);
  hipLaunchKernelGGL(attn_kernel, dim3(M_/32), dim3(256), 0, stream, Q, K, V, out);
}

// Round 2
// 194.876 us; speedup vs baseline: 1.3362x; 1.3362x over previous
//
#include <hip/hip_runtime.h>
#include <stdint.h>

#define B_ 8
#define H_ 128
#define W_ 128
#define D_ 128
#define N_ (H_*W_)
#define M_ (B_*N_)   // 131072 rows total

typedef __attribute__((ext_vector_type(8))) short short8;
typedef __attribute__((ext_vector_type(4))) float floatx4;

typedef const __attribute__((address_space(1))) void* gas_t;
typedef __attribute__((address_space(3))) void* las_t;

__device__ inline unsigned short f2bf(float f){
  union { float f; unsigned int i; } c; c.f = f;
  unsigned int x = c.i;
  x += 0x7FFF + ((x >> 16) & 1);   // RNE
  return (unsigned short)(x >> 16);
}
__device__ inline float bflo(unsigned int u){
  union { unsigned int i; float f; } c; c.i = u << 16; return c.f;
}
__device__ inline float bfhi(unsigned int u){
  union { unsigned int i; float f; } c; c.i = u & 0xFFFF0000u; return c.f;
}

// ---------------- kernel 0: W -> W^T bf16 ----------------
__global__ void wtrans_kernel(const float* __restrict__ Wq, const float* __restrict__ Wk,
                              const float* __restrict__ Wv, unsigned short* __restrict__ Wt){
  const float* src = blockIdx.x == 0 ? Wq : (blockIdx.x == 1 ? Wk : Wv);
  unsigned short* dst = Wt + blockIdx.x * (D_*D_);
  const int i = blockIdx.y * 256 + threadIdx.x;
  const int k = i >> 7, n = i & 127;
  dst[n*D_ + k] = f2bf(src[i]);
}

// ---------------- kernel 1: FUSED QKV projection ----------------
// One block = 128-row tile, computes Q, K, AND V for it -> x read ONCE (was 3x).
__global__ __launch_bounds__(256, 2) void qkv_gemm_kernel(
    const float* __restrict__ x, const unsigned short* __restrict__ Wt,
    const float* __restrict__ bq, const float* __restrict__ bk, const float* __restrict__ bv,
    unsigned short* __restrict__ Q, unsigned short* __restrict__ K, unsigned short* __restrict__ V)
{
  const int rowTile = blockIdx.x;

  __shared__ unsigned short lds[32768];  // 64 KB -> 2 blocks/CU

  const int t = threadIdx.x;
  const int wave = t >> 6, lane = t & 63;

  // ---- A stage (once): fp32 x -> bf16, swizzled ds_write_b128
  {
    const float* xrow = x + (size_t)rowTile * 128 * D_;
    #pragma unroll
    for (int p = 0; p < 8; ++p){
      int s = p*256 + t;
      int r = s >> 4, cp = s & 15, c = cp ^ (r & 7);
      const float* gp = xrow + r*D_ + c*8;
      float4 f0 = *(const float4*)gp;
      float4 f1 = *(const float4*)(gp + 4);
      uint4 pk;
      pk.x = (unsigned)f2bf(f0.x) | ((unsigned)f2bf(f0.y) << 16);
      pk.y = (unsigned)f2bf(f0.z) | ((unsigned)f2bf(f0.w) << 16);
      pk.z = (unsigned)f2bf(f1.x) | ((unsigned)f2bf(f1.y) << 16);
      pk.w = (unsigned)f2bf(f1.z) | ((unsigned)f2bf(f1.w) << 16);
      *(uint4*)&lds[s*8] = pk;
    }
  }

  const int wm = (wave >> 1) * 64, wn = (wave & 1) * 64;
  const int m0 = lane & 15, quad = lane >> 4;

  #pragma unroll
  for (int which = 0; which < 3; ++which){
    const float* bias = which == 0 ? bq : (which == 1 ? bk : bv);
    unsigned short* Out = which == 0 ? Q : (which == 1 ? K : V);
    const unsigned short* Wsel = Wt + which * (D_*D_);

    // ---- B stage: async global->LDS, 16B/lane
    #pragma unroll
    for (int p = 0; p < 8; ++p){
      int s = p*256 + t;                 // 16B chunk id
      int n = s >> 4, cp = s & 15, c = cp ^ (n & 7);
      const unsigned short* gp = Wsel + n*128 + c*8;
      unsigned short* lp = (unsigned short*)lds + 16384 + p*2048 + wave*512;
      __builtin_amdgcn_global_load_lds((gas_t)(const void*)gp, (las_t)(void*)lp, 16, 0, 0);
    }
    __syncthreads();

    floatx4 acc[4][4] = {};
    #pragma unroll
    for (int kk = 0; kk < 4; ++kk){
      short8 a[4], b[4];
      #pragma unroll
      for (int i = 0; i < 4; ++i){
        int row = wm + i*16 + m0;
        int c = (kk*4 + quad) ^ (row & 7);
        a[i] = *(const short8*)&lds[row*128 + c*8];
      }
      #pragma unroll
      for (int j = 0; j < 4; ++j){
        int n = wn + j*16 + m0;
        int c = (kk*4 + quad) ^ (n & 7);
        b[j] = *(const short8*)&lds[16384 + n*128 + c*8];
      }
      #pragma unroll
      for (int i = 0; i < 4; ++i)
        #pragma unroll
        for (int j = 0; j < 4; ++j)
          acc[i][j] = __builtin_amdgcn_mfma_f32_16x16x32_bf16(a[i], b[j], acc[i][j], 0, 0, 0);
    }

    // ---- epilogue: reuse B region (16384 ushorts) in two 64-row halves
    __syncthreads();   // everyone done reading B
    unsigned short* Outp = Out + (size_t)rowTile * 128 * D_;
    #pragma unroll
    for (int half = 0; half < 2; ++half){
      if ((wave >> 1) == half){          // waves owning rows half*64 .. half*64+63
        #pragma unroll
        for (int j = 0; j < 4; ++j){
          const int col = wn + j*16 + m0;
          const float bb = bias[col];
          #pragma unroll
          for (int i = 0; i < 4; ++i){
            #pragma unroll
            for (int r = 0; r < 4; ++r){
              int lrow = i*16 + quad*4 + r;   // local row within half
              lds[16384 + lrow*136 + col] = f2bf(acc[i][j][r] + bb);
            }
          }
        }
      }
      __syncthreads();
      #pragma unroll
      for (int p = 0; p < 4; ++p){
        int rr = p*16 + (t >> 4), cc = t & 15;
        uint4 vv = *(const uint4*)&lds[16384 + rr*136 + cc*8];
        *(uint4*)(Outp + half*8192 + p*2048 + t*8) = vv;
      }
      __syncthreads();
    }
  }
}

// ---------------- kernel 2: 3x3 window attention ----------------
// 8 threads/pixel, 16 dims each. UNCONDITIONAL clamped-address loads (no
// control-flow-merged array defs -> no scratch spill; round-1 version's
// if(ok){load}else{zero} pattern spilled 220 MB under the 128-VGPR cap).
// Zero-pad semantics restored via scalar selects on the score and on pi.
// All 9 K + all 9 V loads batch-issued (36 x 16B in flight per thread);
// launch_bounds(256,2) -> 256-VGPR budget, peak live ~190, no spill.
__global__ __launch_bounds__(256, 2) void attn_kernel(
    const unsigned short* __restrict__ Q, const unsigned short* __restrict__ K,
    const unsigned short* __restrict__ V, float* __restrict__ out)
{
  const int t = threadIdx.x;
  const int e8 = t & 7;                      // which 16-dim chunk
  const int pix = blockIdx.x * 32 + (t >> 3);
  const int w = pix & 127;
  const int h = (pix >> 7) & 127;
  const int bbase = pix & ~(N_ - 1);         // first pixel of this batch image
  const float scale = 0.08838834764831845f;  // 1/sqrt(128)
  const int doff = e8 * 16;
  const size_t off = (size_t)pix * D_ + doff;

  // ---- neighbor pixel indices, clamped into the image (always valid)
  int npix[9]; bool okm[9];
  #pragma unroll
  for (int i = 0; i < 9; ++i){
    const int dy = i/3 - 1, dx = i%3 - 1;
    const int hh = h + dy, ww = w + dx;
    okm[i] = ((unsigned)hh < 128u) && ((unsigned)ww < 128u);
    const int hc = min(max(hh, 0), 127);
    const int wc = min(max(ww, 0), 127);
    npix[i] = bbase + hc*W_ + wc;
  }

  // ---- issue q, then ALL 9 K, then ALL 9 V (unconditional -> batchable)
  uint4 qu0, qu1;
  {
    const unsigned short* qp = Q + off;
    qu0 = *(const uint4*)qp;
    qu1 = *(const uint4*)(qp + 8);
  }
  uint4 ku[9][2];
  #pragma unroll
  for (int i = 0; i < 9; ++i){
    const unsigned short* kp = K + (size_t)npix[i]*D_ + doff;
    ku[i][0] = *(const uint4*)kp;
    ku[i][1] = *(const uint4*)(kp + 8);
  }
  uint4 vu[9][2];
  #pragma unroll
  for (int i = 0; i < 9; ++i){
    const unsigned short* vp = V + (size_t)npix[i]*D_ + doff;
    vu[i][0] = *(const uint4*)vp;
    vu[i][1] = *(const uint4*)(vp + 8);
  }

  // ---- q unpack + scale
  float q[16];
  {
    unsigned uu[8] = {qu0.x, qu0.y, qu0.z, qu0.w, qu1.x, qu1.y, qu1.z, qu1.w};
    #pragma unroll
    for (int e = 0; e < 8; ++e){
      q[e*2]     = bflo(uu[e]) * scale;
      q[e*2 + 1] = bfhi(uu[e]) * scale;
    }
  }

  // ---- partial dot products (16 dims); OOB -> exact 0 via scalar select
  float s[9];
  #pragma unroll
  for (int i = 0; i < 9; ++i){
    unsigned uu[8] = {ku[i][0].x, ku[i][0].y, ku[i][0].z, ku[i][0].w,
                      ku[i][1].x, ku[i][1].y, ku[i][1].z, ku[i][1].w};
    float acc = 0.f;
    #pragma unroll
    for (int e = 0; e < 8; ++e){
      acc += q[e*2]     * bflo(uu[e]);
      acc += q[e*2 + 1] * bfhi(uu[e]);
    }
    s[i] = okm[i] ? acc : 0.f;
  }
  // 8-lane reduce (all 8 lanes of a pixel share okm, so select-then-reduce ok)
  #pragma unroll
  for (int i = 0; i < 9; ++i){
    s[i] += __shfl_xor(s[i], 1, 64);
    s[i] += __shfl_xor(s[i], 2, 64);
    s[i] += __shfl_xor(s[i], 4, 64);
  }

  // ---- softmax (OOB score is exactly 0, participates — ref zero-pad semantics)
  float m = s[0];
  #pragma unroll
  for (int i = 1; i < 9; ++i) m = fmaxf(m, s[i]);
  float p[9]; float l = 0.f;
  #pragma unroll
  for (int i = 0; i < 9; ++i){ p[i] = __expf(s[i] - m); l += p[i]; }
  const float inv = 1.f / l;

  // ---- PV accumulate; OOB contributes 0 via select on pi (v data is garbage
  //      from the clamped address but multiplied by exactly 0)
  float o[16];
  #pragma unroll
  for (int d = 0; d < 16; ++d) o[d] = 0.f;
  #pragma unroll
  for (int i = 0; i < 9; ++i){
    const float pi = okm[i] ? p[i] * inv : 0.f;
    unsigned uu[8] = {vu[i][0].x, vu[i][0].y, vu[i][0].z, vu[i][0].w,
                      vu[i][1].x, vu[i][1].y, vu[i][1].z, vu[i][1].w};
    #pragma unroll
    for (int e = 0; e < 8; ++e){
      o[e*2]     += pi * bflo(uu[e]);
      o[e*2 + 1] += pi * bfhi(uu[e]);
    }
  }

  float* op = out + off;
  #pragma unroll
  for (int c = 0; c < 4; ++c){
    float4 v4 = make_float4(o[c*4], o[c*4+1], o[c*4+2], o[c*4+3]);
    *(float4*)(op + c*4) = v4;
  }
}

extern "C" void kernel_launch(void* const* d_in, const int* in_sizes, int n_in,
                              void* d_out, int out_size, void* d_ws, size_t ws_size,
                              hipStream_t stream)
{
  const float* x  = (const float*)d_in[0];
  const float* Wq = (const float*)d_in[1];
  const float* bq = (const float*)d_in[2];
  const float* Wk = (const float*)d_in[3];
  const float* bk = (const float*)d_in[4];
  const float* Wv = (const float*)d_in[5];
  const float* bv = (const float*)d_in[6];
  float* out = (float*)d_out;

  char* ws = (char*)d_ws;
  unsigned short* Wt = (unsigned short*)ws;                                   // 96 KB
  unsigned short* Q  = (unsigned short*)(ws + (1<<17));
  unsigned short* K  = (unsigned short*)(ws + (1<<17) + (size_t)M_*D_*2);
  unsigned short* V  = (unsigned short*)(ws + (1<<17) + (size_t)2*M_*D_*2);   // ~96.1 MB

  hipLaunchKernelGGL(wtrans_kernel, dim3(3, 64), dim3(256), 0, stream, Wq, Wk, Wv, Wt);
  hipLaunchKernelGGL(qkv_gemm_kernel, dim3(M_/128), dim3(256), 0, stream,
                     x, Wt, bq, bk, bv, Q, K, V);
  hipLaunchKernelGGL(attn_kernel, dim3(M_/32), dim3(256), 0, stream, Q, K, V, out);
}